// Round 10
// baseline (4089.404 us; speedup 1.0000x reference)
//
#include <hip/hip_runtime.h>
#include <stdint.h>

#define N_ 1024
#define T_ 96
#define KRY 96
#define EDG 20480
#define EPS 1e-8f
#define GRID 64

typedef float f4 __attribute__((ext_vector_type(4)));

// ---------------- workspace layout (float offsets) ----------------
enum : size_t {
  O_SN   = 0,
  O_S    = O_SN + (size_t)N_*T_,
  O_MU   = O_S + (size_t)N_*T_,
  O_SD   = O_MU + N_,
  O_NRM  = O_SD + N_,
  O_C0   = O_NRM + N_,
  O_CL   = O_C0 + (size_t)N_*N_,
  O_R    = O_CL + (size_t)N_*N_,
  O_AL   = O_R  + (size_t)N_*N_,
  O_AP   = O_AL + (size_t)N_*N_,
  O_V    = O_AP + (size_t)N_*N_,    // Lanczos basis [KRY][N]
  O_YA   = O_V + (size_t)KRY*N_,    // y vector
  O_ALP  = O_YA + N_,
  O_BET  = O_ALP + 128,
  O_EV   = O_BET + 128,
  O_YS   = O_EV + 128,              // 16 T-eigvecs [16][KRY]
  O_LS   = O_YS + 16*KRY,
  O_BEFF = O_LS + 16,
  O_SCAL = O_BEFF + 64,             // [0]maxL [1]maxP [2..7] mean/inv-std
  O_BARL = O_SCAL + 64,             // Lanczos barrier state (uint, padded: 10 slots x 32)
  O_BARN = O_BARL + 384,            // NMF barrier state
  O_NSLOT= O_BARN + 384,            // (unused now; kept for layout stability)
  O_DOT0 = O_NSLOT + 64,            // CGS pass-0 partial dots [KRY][GRID]
  O_DOT1 = O_DOT0 + (size_t)KRY*GRID, // CGS pass-1 partial dots
  O_RML  = O_DOT1 + (size_t)KRY*GRID,
  O_RDL  = O_RML + N_,
  O_RMP  = O_RDL + N_,
  O_RDP  = O_RMP + N_,
  O_UM   = O_RDP + N_,              // 8 magnitude Ritz vectors [N][8]
  O_WA   = O_UM + (size_t)N_*8,     // NMF W row-major [N][8] ping
  O_WB   = O_WA + (size_t)N_*8,     // pong
  O_SLR  = O_WB + (size_t)N_*8,
  O_SRO  = O_SLR + EDG,
  O_SRE  = O_SRO + EDG,
  O_IDX  = O_SRE + EDG,
  O_END  = O_IDX + EDG
};

__device__ __forceinline__ float hashf(unsigned x){
  x ^= x >> 16; x *= 0x7feb352dU; x ^= x >> 15; x *= 0x846ca68bU; x ^= x >> 16;
  return (float)(x & 0xFFFFFFu) * (1.f/16777216.f) - 0.5f;
}

// Non-temporal (no-allocate) store: cross-block publishes stream to the MALL
// without dirtying the local XCD L2 -> the release fence's buffer_wbl2 has
// (nearly) no dirty lines to flush. Semantics identical to a plain store.
__device__ __forceinline__ void stNT(float* p, float v){
  __builtin_nontemporal_store(v, p);
}

// ---------------- grid barrier (two-level, COUNTED, fence-minimal) ----------
// R9-validated. Leaf (blockIdx&7) gets 8 arrivals/barrier; 8th bumps root;
// spin on root >= 8n. Release fence (L2 writeback, now near-empty thanks to
// nt stores) before arrival; acquire fence (L2 invalidate) after. LDS data
// (R rows, V slice, W tile) survives both fences.
#define BSTR 32
__device__ __forceinline__ void gbar(unsigned* bar, unsigned n){
  __syncthreads();
  if (threadIdx.x == 0){
    __builtin_amdgcn_fence(__ATOMIC_RELEASE, "agent");   // writeback my XCD L2
    unsigned leaf = (blockIdx.x & 7u)*BSTR;
    unsigned lv = __hip_atomic_fetch_add(&bar[leaf], 1u, __ATOMIC_RELAXED, __HIP_MEMORY_SCOPE_AGENT) + 1u;
    if (lv == n*8u)
      __hip_atomic_fetch_add(&bar[8*BSTR], 1u, __ATOMIC_RELAXED, __HIP_MEMORY_SCOPE_AGENT);
    while (__hip_atomic_load(&bar[8*BSTR], __ATOMIC_RELAXED, __HIP_MEMORY_SCOPE_AGENT) < n*8u)
      __builtin_amdgcn_s_sleep(2);
    __builtin_amdgcn_fence(__ATOMIC_ACQUIRE, "agent");   // invalidate stale L2 lines
  }
  __syncthreads();
}

// ---------------- init scalars + barrier state ----------------
__global__ void kInit(float* ws){
  int t = threadIdx.x;
  // covers SCAL(64)+BARL(384)+BARN(384)+NSLOT(64) = 896 contiguous floats
  if (t < 896) ws[O_SCAL + t] = 0.f;
}

// ---------------- node series ----------------
__global__ __launch_bounds__(256) void kSeries(const float* x, float* ws){
  __shared__ float sm[192];
  __shared__ float red[256];
  int n = blockIdx.x, tid = threadIdx.x;
  if (tid < 192){
    float acc = 0.f;
    size_t base = (size_t)n*192 + tid;
    for (int b = 0; b < 16; ++b) acc += x[base + (size_t)b*196608];
    sm[tid] = acc;
  }
  __syncthreads();
  float sval = 0.f;
  if (tid < 96) sval = (sm[2*tid] + sm[2*tid+1]) * (1.f/32.f);
  red[tid] = (tid < 96) ? sval : 0.f; __syncthreads();
  for (int s = 128; s > 0; s >>= 1){ if (tid < s) red[tid] += red[tid+s]; __syncthreads(); }
  float mu = red[0] * (1.f/96.f); __syncthreads();
  red[tid] = (tid < 96) ? sval*sval : 0.f; __syncthreads();
  for (int s = 128; s > 0; s >>= 1){ if (tid < s) red[tid] += red[tid+s]; __syncthreads(); }
  float nrm = sqrtf(red[0]); __syncthreads();
  float dev = sval - mu;
  red[tid] = (tid < 96) ? dev*dev : 0.f; __syncthreads();
  for (int s = 128; s > 0; s >>= 1){ if (tid < s) red[tid] += red[tid+s]; __syncthreads(); }
  float sd = sqrtf(red[0] * (1.f/96.f));
  if (tid < 96){
    ws[O_S  + (size_t)n*96 + tid] = sval;
    ws[O_SN + (size_t)n*96 + tid] = dev / (sd + EPS);
  }
  if (tid == 0){ ws[O_MU+n] = mu; ws[O_SD+n] = sd; ws[O_NRM+n] = nrm; }
}

// ---------------- c0 / cl correlation matrices ----------------
__global__ __launch_bounds__(256) void kCorr(float* ws){
  __shared__ float A[16][97], B[16][97];
  int bi = blockIdx.x, bj = blockIdx.y, tid = threadIdx.x;
  for (int l = tid; l < 16*96; l += 256){
    int r = l / 96, t = l % 96;
    A[r][t] = ws[O_SN + (size_t)(bi*16+r)*96 + t];
    B[r][t] = ws[O_SN + (size_t)(bj*16+r)*96 + t];
  }
  __syncthreads();
  int ti = tid >> 4, tj = tid & 15;
  int i = bi*16 + ti, j = bj*16 + tj;
  float c0 = 0.f, cl = 0.f;
  for (int t = 0; t < 96; ++t) c0 += A[ti][t]*B[tj][t];
  for (int t = 0; t < 95; ++t) cl += A[ti][t]*B[tj][t+1];
  ws[O_C0 + (size_t)i*N_ + j] = c0 * (1.f/96.f);
  ws[O_CL + (size_t)i*N_ + j] = cl * (1.f/95.f);
}

// ---------------- R ----------------
__global__ __launch_bounds__(256) void kR(float* ws){
  __shared__ float tl[32][33];
  int bi = blockIdx.x, bj = blockIdx.y, tid = threadIdx.x;
  for (int l = tid; l < 1024; l += 256){
    int r = l >> 5, c = l & 31;
    tl[r][c] = ws[O_CL + (size_t)(bj*32+r)*N_ + bi*32 + c];
  }
  __syncthreads();
  for (int l = tid; l < 1024; l += 256){
    int il = l >> 5, jl = l & 31;
    int i = bi*32 + il, j = bj*32 + jl;
    float c0 = ws[O_C0 + (size_t)i*N_ + j];
    float cl = ws[O_CL + (size_t)i*N_ + j];
    float clt = tl[jl][il];
    ws[O_R + (size_t)i*N_ + j] = 0.5f*(fabsf(c0) + fabsf(0.5f*(cl + clt)));
  }
}

// ---------------- per-row top-20 ----------------
__global__ __launch_bounds__(256) void kTopK(float* ws){
  __shared__ float v[1024];
  __shared__ float rv[256];
  __shared__ int ri[256];
  int r = blockIdx.x, tid = threadIdx.x;
  for (int l = tid; l < 1024; l += 256) v[l] = ws[O_R + (size_t)r*N_ + l];
  __syncthreads();
  if (tid == 0) v[r] = -3.4e38f;
  __syncthreads();
  int* idx = (int*)(ws + O_IDX);
  for (int t = 0; t < 20; ++t){
    float best = -3.4e38f; int bi = 1 << 30;
    for (int l = tid; l < 1024; l += 256){
      float vv = v[l];
      if (vv > best || (vv == best && l < bi)){ best = vv; bi = l; }
    }
    rv[tid] = best; ri[tid] = bi; __syncthreads();
    for (int s = 128; s > 0; s >>= 1){
      if (tid < s){
        if (rv[tid+s] > rv[tid] || (rv[tid+s] == rv[tid] && ri[tid+s] < ri[tid])){
          rv[tid] = rv[tid+s]; ri[tid] = ri[tid+s];
        }
      }
      __syncthreads();
    }
    if (tid == 0){ idx[r*20 + t] = ri[0]; v[ri[0]] = -3.4e38f; }
    __syncthreads();
  }
}

// ---------------- persistent Lanczos: 96 steps, CGS2, 3 barriers/step --------
// vs R9: (1) cross-block publishes (dot0/dot1, y) use nt stores -> release
// fence has no dirty lines; (2) slots path eliminated -- phase A computes
// ||y||^2 directly from the y broadcast it already does (one fewer dependent
// MALL round per step; phase C loses its norm tail). Everything else verbatim.
__global__ __launch_bounds__(256) void kLanczos(float* ws){
  unsigned* bar = (unsigned*)(ws + O_BARL);
  __shared__ __align__(16) float Rl[16][1024];   // 64 KB: this block's R rows
  __shared__ float Vsl[KRY][16];                 // 6 KB: own V column-slice
  __shared__ __align__(16) float vsh[1024];
  __shared__ float red[272];
  __shared__ float yls[16];      // own slice of y
  __shared__ float csh[KRY];     // reduced CGS coefficients
  const int b = blockIdx.x, tid = threadIdx.x;
  const int i0 = b*16;
  float* dot0  = ws + O_DOT0;
  float* dot1  = ws + O_DOT1;
  float* y     = ws + O_YA;
  unsigned nb = 0;   // barrier index (1-based at each call)

  // prologue: stage R rows into LDS (once), v0 into y slice
  {
    const f4* src = (const f4*)(ws + O_R + (size_t)i0*N_);   // 16 contiguous rows
    f4* dst = (f4*)&Rl[0][0];
    for (int l = tid; l < 4096; l += 256) dst[l] = src[l];
  }
  if (tid < 16)
    stNT(&y[i0 + tid], hashf((unsigned)(i0 + tid + 12345)));
  gbar(bar, ++nb);

  for (int k = 0; k < KRY; ++k){
    // ---- phase A: read y (f4), norm from it, matvec (LDS R), pass-0 partials
    {
      f4 yq = ((const f4*)y)[tid];                 // full y, one MALL round
      float ss = yq.x*yq.x + yq.y*yq.y + yq.z*yq.z + yq.w*yq.w;
      red[tid] = ss; __syncthreads();
      for (int s = 128; s > 0; s >>= 1){ if (tid < s) red[tid] += red[tid+s]; __syncthreads(); }
      float inv = rsqrtf(fmaxf(red[0], 1e-30f));
      __syncthreads();
      ((f4*)vsh)[tid] = yq * inv;
      __syncthreads();
      if (tid < 16){
        float vk = vsh[i0 + tid];
        ws[O_V + (size_t)k*N_ + i0 + tid] = vk;   // for kRitz
        Vsl[k][tid] = vk;
      }
      int wave = tid >> 6, lane = tid & 63;
      for (int rr = 0; rr < 4; ++rr){
        const float* row = &Rl[wave*4 + rr][0];
        float acc = 0.f;
        for (int t2 = lane; t2 < 1024; t2 += 64) acc += row[t2]*vsh[t2];
        for (int off = 32; off > 0; off >>= 1) acc += __shfl_down(acc, off, 64);
        if (lane == 0) yls[wave*4 + rr] = acc;
      }
      __syncthreads();
      if (tid <= k){
        float acc = 0.f;
        #pragma unroll
        for (int q = 0; q < 16; ++q) acc += Vsl[tid][q]*yls[q];
        stNT(&dot0[tid*GRID + b], acc);
      }
    }
    gbar(bar, ++nb);
    // ---- phase B: reduce c (+alpha/beta), local axpy0, pass-1 partials -----
    {
      if (tid <= k){
        const float* pr = dot0 + (size_t)tid*GRID;
        float acc = 0.f;
        #pragma unroll
        for (int q = 0; q < GRID; ++q) acc += pr[q];
        csh[tid] = acc;
        if (b == 0){
          if (tid == k)   ws[O_ALP + k] = acc;
          if (tid == k-1) ws[O_BET + k] = acc;
        }
      }
      __syncthreads();
      if (k == KRY-1) break;   // last step: only alpha/beta needed
      int il = tid & 15, chunk = tid >> 4;
      float part = 0.f;
      for (int j = chunk; j <= k; j += 16) part += csh[j]*Vsl[j][il];
      red[il*17 + chunk] = part;
      __syncthreads();
      if (tid < 16){
        float corr = 0.f;
        #pragma unroll
        for (int q = 0; q < 16; ++q) corr += red[tid*17 + q];
        yls[tid] -= corr;
      }
      __syncthreads();
      if (tid <= k){
        float acc = 0.f;
        #pragma unroll
        for (int q = 0; q < 16; ++q) acc += Vsl[tid][q]*yls[q];
        stNT(&dot1[tid*GRID + b], acc);
      }
    }
    gbar(bar, ++nb);
    // ---- phase C: reduce c', local axpy1, publish y slice ----
    {
      if (tid <= k){
        const float* pr = dot1 + (size_t)tid*GRID;
        float acc = 0.f;
        #pragma unroll
        for (int q = 0; q < GRID; ++q) acc += pr[q];
        csh[tid] = acc;
      }
      __syncthreads();
      int il = tid & 15, chunk = tid >> 4;
      float part = 0.f;
      for (int j = chunk; j <= k; j += 16) part += csh[j]*Vsl[j][il];
      red[il*17 + chunk] = part;
      __syncthreads();
      if (tid < 16){
        float corr = 0.f;
        #pragma unroll
        for (int q = 0; q < 16; ++q) corr += red[tid*17 + q];
        float nv = yls[tid] - corr;
        yls[tid] = nv;
        stNT(&y[i0 + tid], nv);
      }
    }
    gbar(bar, ++nb);
  }
}

// ---------------- T eigensolve (KRY=96): bisection + inverse iteration ----------------
__global__ __launch_bounds__(256) void kEigen(float* ws, const float* srcsig, const float* srcB){
  __shared__ float a[KRY], bt[KRY], b2[KRY], ev[KRY];
  __shared__ float Dw[16][KRY], U1w[16][KRY], U2w[16][KRY], Xw[16][KRY];
  __shared__ int slotidx[16];
  __shared__ float slam[16];
  __shared__ float glo_s, ghi_s;
  int tid = threadIdx.x;
  if (tid < KRY){
    a[tid] = ws[O_ALP + tid];
    float b = (tid >= 1) ? ws[O_BET + tid] : 0.f;
    bt[tid] = b; b2[tid] = b*b;
  }
  __syncthreads();
  if (tid == 0){
    float lo = 3.4e38f, hi = -3.4e38f;
    for (int i = 0; i < KRY; ++i){
      float r = fabsf(bt[i]) + ((i < KRY-1) ? fabsf(bt[i+1]) : 0.f);
      lo = fminf(lo, a[i] - r); hi = fmaxf(hi, a[i] + r);
    }
    glo_s = lo - 1.f; ghi_s = hi + 1.f;
  }
  __syncthreads();
  if (tid < KRY){
    float lo = glo_s, hi = ghi_s;
    for (int it = 0; it < 60; ++it){
      float mid = 0.5f*(lo + hi);
      int cnt = 0; float d = 1.f;
      for (int kk = 0; kk < KRY; ++kk){
        d = (a[kk] - mid) - ((kk > 0) ? b2[kk]/d : 0.f);
        if (d < 0.f) cnt++;
        if (fabsf(d) < 1e-20f) d = -1e-20f;
      }
      if (cnt <= tid) lo = mid; else hi = mid;
    }
    ev[tid] = 0.5f*(lo + hi);
    ws[O_EV + tid] = ev[tid];
  }
  __syncthreads();
  if (tid == 0){
    int hiI = KRY-1, loI = 0;
    float topv[16]; int magidx[16];
    for (int t = 0; t < 16; ++t){
      if (fabsf(ev[hiI]) >= fabsf(ev[loI])) magidx[t] = hiI--;
      else magidx[t] = loI++;
      topv[t] = fabsf(ev[magidx[t]]);
    }
    for (int s = 0; s < 8; ++s){ slotidx[s] = magidx[s]; slam[s] = ev[magidx[s]]; }
    for (int s = 0; s < 8; ++s){ slotidx[8+s] = KRY-8 + s; slam[8+s] = ev[KRY-8+s]; }
    float t0 = topv[0] + EPS;
    float sig[4];
    for (int m = 0; m < 4; ++m){
      float acc = 0.f;
      for (int t = 0; t < 16; ++t){
        float x = topv[t]/t0, p = x;
        for (int q = 0; q < m; ++q) p *= x;
        acc += p;
      }
      sig[m] = acc * (1.f/16.f);
    }
    float dist[3];
    for (int m = 0; m < 3; ++m){
      float acc = 0.f;
      for (int kq = 0; kq < 4; ++kq){ float dd = srcsig[m*4+kq] - sig[kq]; acc += dd*dd; }
      dist[m] = acc;
    }
    float mx = fmaxf(fmaxf(-dist[0], -dist[1]), -dist[2]);
    float e0 = expf(-dist[0]-mx), e1 = expf(-dist[1]-mx), e2 = expf(-dist[2]-mx);
    float sinv = 1.f/(e0+e1+e2);
    float rho0 = e0*sinv, rho1 = e1*sinv, rho2 = e2*sinv;
    for (int rr = 0; rr < 8; ++rr)
      for (int ss = 0; ss < 8; ++ss)
        ws[O_BEFF + rr*8 + ss] = rho0*srcB[rr*8+ss] + rho1*srcB[64+rr*8+ss] + rho2*srcB[128+rr*8+ss];
    for (int s = 0; s < 16; ++s) ws[O_LS + s] = slam[s];
  }
  __syncthreads();
  if (tid < 16){
    int s = tid, ei = slotidx[s];
    float lam = ev[ei];
    for (int pass = 0; pass < 2; ++pass){
      for (int i = 0; i < KRY; ++i){
        Dw[s][i] = a[i] - lam;
        U1w[s][i] = (i < KRY-1) ? bt[i+1] : 0.f;
        U2w[s][i] = 0.f;
        if (pass == 0) Xw[s][i] = hashf((unsigned)(ei*1024 + i + 777));
      }
      for (int i = 0; i < KRY-1; ++i){
        float p1 = Dw[s][i], q1 = U1w[s][i], r1 = U2w[s][i], x1 = Xw[s][i];
        float p2 = bt[i+1], q2 = Dw[s][i+1], rr2 = U1w[s][i+1], x2 = Xw[s][i+1];
        if (fabsf(p2) > fabsf(p1)){
          float t;
          t=p1;p1=p2;p2=t; t=q1;q1=q2;q2=t; t=r1;r1=rr2;rr2=t; t=x1;x1=x2;x2=t;
        }
        if (fabsf(p1) < 1e-20f) p1 = (p1 < 0.f) ? -1e-20f : 1e-20f;
        float m = p2/p1;
        Dw[s][i]=p1; U1w[s][i]=q1; U2w[s][i]=r1; Xw[s][i]=x1;
        Dw[s][i+1] = q2 - m*q1; U1w[s][i+1] = rr2 - m*r1; Xw[s][i+1] = x2 - m*x1;
      }
      {
        float dd = Dw[s][KRY-1]; if (fabsf(dd) < 1e-20f) dd = 1e-20f;
        Xw[s][KRY-1] = Xw[s][KRY-1]/dd;
      }
      {
        float dd = Dw[s][KRY-2]; if (fabsf(dd) < 1e-20f) dd = 1e-20f;
        Xw[s][KRY-2] = (Xw[s][KRY-2] - U1w[s][KRY-2]*Xw[s][KRY-1])/dd;
      }
      for (int i = KRY-3; i >= 0; --i){
        float dd = Dw[s][i]; if (fabsf(dd) < 1e-20f) dd = 1e-20f;
        Xw[s][i] = (Xw[s][i] - U1w[s][i]*Xw[s][i+1] - U2w[s][i]*Xw[s][i+2])/dd;
      }
      float nn = 0.f;
      for (int i = 0; i < KRY; ++i) nn += Xw[s][i]*Xw[s][i];
      float inv = rsqrtf(fmaxf(nn, 1e-37f));
      for (int i = 0; i < KRY; ++i) Xw[s][i] *= inv;
    }
  }
  __syncthreads();
  if (tid == 0){
    for (int s = 1; s < 16; ++s)
      for (int t = 0; t < s; ++t){
        if (slotidx[t] == slotidx[s]) continue;
        if (fabsf(slam[t] - slam[s]) > 1e-2f) continue;
        float dp = 0.f;
        for (int i = 0; i < KRY; ++i) dp += Xw[s][i]*Xw[t][i];
        for (int i = 0; i < KRY; ++i) Xw[s][i] -= dp*Xw[t][i];
        float nn = 0.f;
        for (int i = 0; i < KRY; ++i) nn += Xw[s][i]*Xw[s][i];
        float inv = rsqrtf(fmaxf(nn, 1e-37f));
        for (int i = 0; i < KRY; ++i) Xw[s][i] *= inv;
      }
  }
  __syncthreads();
  for (int l = tid; l < 16*KRY; l += 256) ws[O_YS + l] = Xw[l/KRY][l%KRY];
}

// ---------------- Ritz vectors: Umag (slots 0..7), W0 row-major (slots 8..15) ----------------
__global__ __launch_bounds__(256) void kRitz(float* ws){
  __shared__ float ysh[16][KRY];
  __shared__ float lam[16];
  int tid = threadIdx.x;
  for (int l = tid; l < 16*KRY; l += 256) ysh[l/KRY][l%KRY] = ws[O_YS + l];
  if (tid < 16) lam[tid] = ws[O_LS + tid];
  __syncthreads();
  int i = blockIdx.x*256 + tid;
  float acc[16];
  #pragma unroll
  for (int s = 0; s < 16; ++s) acc[s] = 0.f;
  for (int k = 0; k < KRY; ++k){
    float v = ws[O_V + (size_t)k*N_ + i];
    #pragma unroll
    for (int s = 0; s < 16; ++s) acc[s] += v*ysh[s][k];
  }
  #pragma unroll
  for (int s = 0; s < 8; ++s) ws[O_UM + (size_t)i*8 + s] = acc[s];
  #pragma unroll
  for (int c = 0; c < 8; ++c) ws[O_WA + (size_t)i*8 + c] = sqrtf(fabsf(lam[8+c]))*fabsf(acc[8+c]);
}

// ---------------- |L| + global max ----------------
__global__ __launch_bounds__(256) void kL(float* ws){
  __shared__ float Ua[32][8], Ub[32][8], lam[8];
  __shared__ float red[256];
  int bi = blockIdx.x, bj = blockIdx.y, tid = threadIdx.x;
  if (tid < 8) lam[tid] = ws[O_LS + tid];
  int r = tid >> 3, c = tid & 7;
  Ua[r][c] = ws[O_UM + (size_t)(bi*32+r)*8 + c];
  Ub[r][c] = ws[O_UM + (size_t)(bj*32+r)*8 + c];
  __syncthreads();
  float bmax = 0.f;
  for (int l = tid; l < 1024; l += 256){
    int il = l >> 5, jl = l & 31;
    int i = bi*32 + il, j = bj*32 + jl;
    float acc = 0.f;
    #pragma unroll
    for (int q = 0; q < 8; ++q) acc += lam[q]*Ua[il][q]*Ub[jl][q];
    float v = fabsf(acc);
    if (i == j) v = 0.f;
    ws[O_AL + (size_t)i*N_ + j] = v;
    bmax = fmaxf(bmax, v);
  }
  red[tid] = bmax; __syncthreads();
  for (int s = 128; s > 0; s >>= 1){ if (tid < s) red[tid] = fmaxf(red[tid], red[tid+s]); __syncthreads(); }
  if (tid == 0) atomicMax((int*)(ws + O_SCAL + 0), __float_as_int(red[0]));
}

// ---------------- per-row scaled max + softmax denom ----------------
__global__ __launch_bounds__(256) void kRowStats(float* ws, int which){
  __shared__ float red[256];
  size_t src = which ? O_AP : O_AL;
  float mxall = __int_as_float(((int*)(ws + O_SCAL))[which]);
  float d = 1.f/(mxall + EPS);
  int r = blockIdx.x, tid = threadIdx.x;
  const float* row = ws + src + (size_t)r*N_;
  float m = 0.f;
  for (int l = tid; l < 1024; l += 256) m = fmaxf(m, row[l]);
  red[tid] = m; __syncthreads();
  for (int s = 128; s > 0; s >>= 1){ if (tid < s) red[tid] = fmaxf(red[tid], red[tid+s]); __syncthreads(); }
  float rmax = red[0]*d; __syncthreads();
  float acc = 0.f;
  for (int l = tid; l < 1024; l += 256){ float v = row[l]; if (v != 0.f) acc += expf(v*d - rmax); }
  red[tid] = acc; __syncthreads();
  for (int s = 128; s > 0; s >>= 1){ if (tid < s) red[tid] += red[tid+s]; __syncthreads(); }
  if (tid == 0){
    ws[(which ? O_RMP : O_RML) + r] = rmax;
    ws[(which ? O_RDP : O_RDL) + r] = red[0];
  }
}

// ---------------- persistent NMF: 80 clamped-GD iterations ----------------
// R rows in LDS (fence-immune); W padded to stride 9; counted barrier;
// W publish via nt store (no L2 dirty lines at the release fence).
__global__ __launch_bounds__(256) void kNmf(float* ws){
  unsigned* bar = (unsigned*)(ws + O_BARN);
  __shared__ __align__(16) float Rl[16][1028];   // 64.3 KB, stride 1028 spreads banks
  __shared__ float Wl[1024][9];   // 36 KB, padded stride
  __shared__ float G[64];
  __shared__ float red2[256];
  int b = blockIdx.x, tid = threadIdx.x;
  int r0 = b*16;
  {
    for (int l = tid; l < 4096; l += 256){
      int r = l >> 8, t4 = l & 255;
      ((f4*)&Rl[r][0])[t4] = ((const f4*)(ws + O_R + (size_t)(r0+r)*N_))[t4];
    }
  }
  for (int it = 0; it < 80; ++it){
    const float* Win = ws + ((it & 1) ? O_WB : O_WA);
    float* Wout      = ws + ((it & 1) ? O_WA : O_WB);
    for (int l = tid; l < 8192; l += 256) Wl[l >> 3][l & 7] = Win[l];
    __syncthreads();
    // G = W^T W  (redundant per block, deterministic)
    {
      int p = tid >> 2, q = tid & 3;
      int rr = p >> 3, cc = p & 7;
      float acc = 0.f;
      for (int t = q*256; t < q*256 + 256; ++t) acc += Wl[t][rr]*Wl[t][cc];
      red2[tid] = acc; __syncthreads();
      if (q == 0) G[p] = red2[tid] + red2[tid+1] + red2[tid+2] + red2[tid+3];
      __syncthreads();
    }
    // RW + update for own 16 rows (R from LDS)
    {
      int half = tid & 1;
      int pr = tid >> 1;            // 0..127 = (lr, j)
      int lr = pr >> 3, j = pr & 7;
      int grow = r0 + lr;
      const float* rrow = &Rl[lr][0];
      float acc = 0.f;
      for (int t = half*512; t < half*512 + 512; ++t) acc += rrow[t]*Wl[t][j];
      red2[tid] = acc; __syncthreads();
      if (half == 0){
        float rw = red2[tid] + red2[tid+1];
        float wg = 0.f;
        #pragma unroll
        for (int c = 0; c < 8; ++c) wg += Wl[grow][c]*G[c*8 + j];
        float val = Wl[grow][j] - 0.2f*(wg - rw);
        stNT(&Wout[(size_t)grow*8 + j], fmaxf(val, 0.f));
      }
      __syncthreads();
    }
    if (it != 79) gbar(bar, (unsigned)(it + 1));   // kernel boundary covers the last iter
  }
}

// ---------------- |W Beff W^T| + global max (Wb folded in) ----------------
__global__ __launch_bounds__(256) void kP(float* ws){
  __shared__ float B[64];
  __shared__ float Wa[8][32], Wb2[8][32];
  __shared__ float red[256];
  int bi = blockIdx.x, bj = blockIdx.y, tid = threadIdx.x;
  if (tid < 64) B[tid] = ws[O_BEFF + tid];
  __syncthreads();
  {
    int c = tid >> 5, il = tid & 31;
    Wb2[c][il] = ws[O_WA + (size_t)(bj*32+il)*8 + c];
  }
  __syncthreads();
  {
    int r = tid >> 5, il = tid & 31;
    float acc = 0.f;
    #pragma unroll
    for (int c = 0; c < 8; ++c) acc += ws[O_WA + (size_t)(bi*32+il)*8 + c]*B[c*8 + r];
    Wa[r][il] = acc;
  }
  __syncthreads();
  float bmax = 0.f;
  for (int l = tid; l < 1024; l += 256){
    int il = l >> 5, jl = l & 31;
    int i = bi*32+il, j = bj*32+jl;
    float acc = 0.f;
    #pragma unroll
    for (int q = 0; q < 8; ++q) acc += Wa[q][il]*Wb2[q][jl];
    float v = fabsf(acc);
    if (i == j) v = 0.f;
    ws[O_AP + (size_t)i*N_ + j] = v;
    bmax = fmaxf(bmax, v);
  }
  red[tid] = bmax; __syncthreads();
  for (int s = 128; s > 0; s >>= 1){ if (tid < s) red[tid] = fmaxf(red[tid], red[tid+s]); __syncthreads(); }
  if (tid == 0) atomicMax((int*)(ws + O_SCAL + 1), __float_as_int(red[0]));
}

// ---------------- edge scores ----------------
__global__ __launch_bounds__(256) void kEdges(float* ws, const float* w1, const float* b1,
                                              const float* w2, const float* b2){
  __shared__ float W1[256], B1[32], W2[32], B2;
  int tid = threadIdx.x;
  if (tid < 256) W1[tid] = w1[tid];
  if (tid < 32){ B1[tid] = b1[tid]; W2[tid] = w2[tid]; }
  if (tid == 0) B2 = b2[0];
  __syncthreads();
  int e = blockIdx.x*256 + tid;
  if (e >= EDG) return;
  int r = e/20;
  int c = ((const int*)(ws + O_IDX))[e];
  float dL = 1.f/(__int_as_float(((int*)(ws+O_SCAL))[0]) + EPS);
  float aL = ws[O_AL + (size_t)r*N_ + c];
  float slr = 0.f;
  if (aL != 0.f){ float den = ws[O_RDL + r]; if (den > 0.f) slr = expf(aL*dL - ws[O_RML + r])/den; }
  float dP = 1.f/(__int_as_float(((int*)(ws+O_SCAL))[1]) + EPS);
  float aP = ws[O_AP + (size_t)r*N_ + c];
  float sro = 0.f;
  if (aP != 0.f){ float den = ws[O_RDP + r]; if (den > 0.f) sro = expf(aP*dP - ws[O_RMP + r])/den; }
  float dots = 0.f;
  const float* srow = ws + O_S + (size_t)r*T_;
  const float* scol = ws + O_S + (size_t)c*T_;
  for (int t = 0; t < 96; ++t) dots += srow[t]*scol[t];
  float cosm = dots/(ws[O_NRM+r]*ws[O_NRM+c] + EPS);
  float f[8];
  f[0] = ws[O_C0 + (size_t)r*N_ + c];
  f[1] = ws[O_CL + (size_t)r*N_ + c];
  f[2] = ws[O_CL + (size_t)c*N_ + r];
  f[3] = cosm;
  f[4] = ws[O_MU + r]; f[5] = ws[O_MU + c];
  f[6] = ws[O_SD + r]; f[7] = ws[O_SD + c];
  float sres = B2;
  for (int jj = 0; jj < 32; ++jj){
    float h = B1[jj];
    #pragma unroll
    for (int q = 0; q < 8; ++q) h += f[q]*W1[q*32 + jj];
    h = fmaxf(h, 0.f);
    sres += h*W2[jj];
  }
  ws[O_SLR + e] = slr; ws[O_SRO + e] = sro; ws[O_SRE + e] = sres;
}

// ---------------- mean / inv-std of score arrays ----------------
__global__ __launch_bounds__(1024) void kStats(float* ws){
  __shared__ float red[1024];
  int tid = threadIdx.x;
  for (int arr = 0; arr < 3; ++arr){
    const float* x = (arr == 0) ? ws + O_SLR : ((arr == 1) ? ws + O_SRO : ws + O_SRE);
    float acc = 0.f;
    for (int l = tid; l < EDG; l += 1024) acc += x[l];
    red[tid] = acc; __syncthreads();
    for (int s = 512; s > 0; s >>= 1){ if (tid < s) red[tid] += red[tid+s]; __syncthreads(); }
    float mean = red[0]/(float)EDG; __syncthreads();
    float acc2 = 0.f;
    for (int l = tid; l < EDG; l += 1024){ float d = x[l]-mean; acc2 += d*d; }
    red[tid] = acc2; __syncthreads();
    for (int s = 512; s > 0; s >>= 1){ if (tid < s) red[tid] += red[tid+s]; __syncthreads(); }
    if (tid == 0){
      float var = red[0]/(float)EDG;
      ws[O_SCAL + 2 + arr*2] = mean;
      ws[O_SCAL + 3 + arr*2] = 1.f/(sqrtf(var) + EPS);
    }
    __syncthreads();
  }
}

// ---------------- final output ----------------
__global__ __launch_bounds__(256) void kOut(float* ws, float* out){
  __shared__ __align__(16) float row[1024];
  __shared__ float sv[20];
  __shared__ int cols[20];
  int r = blockIdx.x, tid = threadIdx.x;
  for (int l = tid; l < 1024; l += 256) row[l] = 0.f;
  if (tid < 20){
    int e = r*20 + tid;
    float m1 = ws[O_SCAL+2], k1 = ws[O_SCAL+3];
    float m2 = ws[O_SCAL+4], k2 = ws[O_SCAL+5];
    float m3 = ws[O_SCAL+6], k3 = ws[O_SCAL+7];
    float v = 0.3f*(ws[O_SLR+e]-m1)*k1 + 0.4f*(ws[O_SRO+e]-m2)*k2 + 0.1f*(ws[O_SRE+e]-m3)*k3;
    sv[tid] = 1.f/(1.f + expf(-v));
    cols[tid] = ((const int*)(ws + O_IDX))[e];
  }
  __syncthreads();
  if (tid == 0){
    float mx = sv[0];
    for (int q = 1; q < 20; ++q) mx = fmaxf(mx, sv[q]);
    float den = 0.f; float ex[20];
    for (int q = 0; q < 20; ++q){ ex[q] = expf(sv[q]-mx); den += ex[q]; }
    float inv = 1.f/den;
    for (int q = 0; q < 20; ++q) row[cols[q]] = ex[q]*inv;
  }
  __syncthreads();
  const float4* r4 = (const float4*)row;
  for (int b = 0; b < 16; ++b){
    float4* dst = (float4*)(out + (size_t)b*1048576 + (size_t)r*1024);
    dst[tid] = r4[tid];
  }
}

extern "C" void kernel_launch(void* const* d_in, const int* in_sizes, int n_in,
                              void* d_out, int out_size, void* d_ws, size_t ws_size,
                              hipStream_t stream) {
  (void)in_sizes; (void)n_in; (void)out_size; (void)ws_size;
  const float* x   = (const float*)d_in[0];
  const float* sig = (const float*)d_in[2];
  const float* rB  = (const float*)d_in[3];
  const float* w1  = (const float*)d_in[4];
  const float* b1  = (const float*)d_in[5];
  const float* w2  = (const float*)d_in[6];
  const float* b2  = (const float*)d_in[7];
  float* w = (float*)d_ws;
  float* out = (float*)d_out;

  kInit<<<1, 1024, 0, stream>>>(w);
  kSeries<<<1024, 256, 0, stream>>>(x, w);
  kCorr<<<dim3(64,64), 256, 0, stream>>>(w);
  kR<<<dim3(32,32), 256, 0, stream>>>(w);
  kTopK<<<1024, 256, 0, stream>>>(w);

  kLanczos<<<GRID, 256, 0, stream>>>(w);     // 96-step CGS2 Lanczos, nt publishes
  kEigen<<<1, 256, 0, stream>>>(w, sig, rB);
  kRitz<<<4, 256, 0, stream>>>(w);

  kL<<<dim3(32,32), 256, 0, stream>>>(w);
  kRowStats<<<1024, 256, 0, stream>>>(w, 0);

  kNmf<<<GRID, 256, 0, stream>>>(w);         // 80 iterations, nt publishes
  kP<<<dim3(32,32), 256, 0, stream>>>(w);
  kRowStats<<<1024, 256, 0, stream>>>(w, 1);

  kEdges<<<80, 256, 0, stream>>>(w, w1, b1, w2, b2);
  kStats<<<1, 1024, 0, stream>>>(w);
  kOut<<<1024, 256, 0, stream>>>(w, out);
}

// Round 11
// 3891.590 us; speedup vs baseline: 1.0508x; 1.0508x over previous
//
#include <hip/hip_runtime.h>
#include <stdint.h>

#define N_ 1024
#define T_ 96
#define KRY 96
#define EDG 20480
#define EPS 1e-8f
#define GRID 64

typedef float f4 __attribute__((ext_vector_type(4)));

// ---------------- workspace layout (float offsets) ----------------
enum : size_t {
  O_SN   = 0,
  O_S    = O_SN + (size_t)N_*T_,
  O_MU   = O_S + (size_t)N_*T_,
  O_SD   = O_MU + N_,
  O_NRM  = O_SD + N_,
  O_C0   = O_NRM + N_,
  O_CL   = O_C0 + (size_t)N_*N_,
  O_R    = O_CL + (size_t)N_*N_,
  O_AL   = O_R  + (size_t)N_*N_,
  O_AP   = O_AL + (size_t)N_*N_,
  O_V    = O_AP + (size_t)N_*N_,    // Lanczos basis [KRY][N]
  O_YA   = O_V + (size_t)KRY*N_,    // y vector
  O_ALP  = O_YA + N_,
  O_BET  = O_ALP + 128,
  O_EV   = O_BET + 128,
  O_YS   = O_EV + 128,              // 16 T-eigvecs [16][KRY]
  O_LS   = O_YS + 16*KRY,
  O_BEFF = O_LS + 16,
  O_SCAL = O_BEFF + 64,             // [0]maxL [1]maxP [2..7] mean/inv-std
  O_BARL = O_SCAL + 64,             // Lanczos barrier state (uint, padded: 10 slots x 32)
  O_BARN = O_BARL + 384,            // NMF barrier state
  O_NSLOT= O_BARN + 384,            // 64 partial-norm slots
  O_DOT0 = O_NSLOT + 64,            // CGS pass-0 partial dots [KRY][GRID]
  O_DOT1 = O_DOT0 + (size_t)KRY*GRID, // CGS pass-1 partial dots
  O_RML  = O_DOT1 + (size_t)KRY*GRID,
  O_RDL  = O_RML + N_,
  O_RMP  = O_RDL + N_,
  O_RDP  = O_RMP + N_,
  O_UM   = O_RDP + N_,              // 8 magnitude Ritz vectors [N][8]
  O_WA   = O_UM + (size_t)N_*8,     // NMF W row-major [N][8] ping
  O_WB   = O_WA + (size_t)N_*8,     // pong
  O_SLR  = O_WB + (size_t)N_*8,
  O_SRO  = O_SLR + EDG,
  O_SRE  = O_SRO + EDG,
  O_IDX  = O_SRE + EDG,
  O_END  = O_IDX + EDG
};

__device__ __forceinline__ float hashf(unsigned x){
  x ^= x >> 16; x *= 0x7feb352dU; x ^= x >> 15; x *= 0x846ca68bU; x ^= x >> 16;
  return (float)(x & 0xFFFFFFu) * (1.f/16777216.f) - 0.5f;
}

// ---------------- grid barrier (two-level, generation-based, fence-minimal) ----
// Proven-best (R7 bench: 3897 us total). One release fence (L2 writeback)
// before arrival, one acquire fence (L2 invalidate) after departure; relaxed
// RMWs on 128B-padded counters. LDS contents survive the fences.
#define BSTR 32
__device__ __forceinline__ void gbar(unsigned* bar){
  __syncthreads();
  if (threadIdx.x == 0){
    __builtin_amdgcn_fence(__ATOMIC_RELEASE, "agent");   // writeback my XCD L2
    unsigned g = __hip_atomic_load(&bar[9*BSTR], __ATOMIC_RELAXED, __HIP_MEMORY_SCOPE_AGENT);
    unsigned leaf = (blockIdx.x & 7u)*BSTR;
    unsigned lv = __hip_atomic_fetch_add(&bar[leaf], 1u, __ATOMIC_RELAXED, __HIP_MEMORY_SCOPE_AGENT) + 1u;
    if (lv == (g+1u)*8u){
      unsigned rv = __hip_atomic_fetch_add(&bar[8*BSTR], 1u, __ATOMIC_RELAXED, __HIP_MEMORY_SCOPE_AGENT) + 1u;
      if (rv == (g+1u)*8u)
        __hip_atomic_store(&bar[9*BSTR], g+1u, __ATOMIC_RELAXED, __HIP_MEMORY_SCOPE_AGENT);
    }
    while (__hip_atomic_load(&bar[9*BSTR], __ATOMIC_RELAXED, __HIP_MEMORY_SCOPE_AGENT) == g)
      __builtin_amdgcn_s_sleep(2);
    __builtin_amdgcn_fence(__ATOMIC_ACQUIRE, "agent");   // invalidate stale L2 lines
  }
  __syncthreads();
}

// ---------------- init scalars + barrier state ----------------
__global__ void kInit(float* ws){
  int t = threadIdx.x;
  // covers SCAL(64)+BARL(384)+BARN(384)+NSLOT(64) = 896 contiguous floats
  if (t < 896) ws[O_SCAL + t] = 0.f;
}

// ---------------- node series ----------------
__global__ __launch_bounds__(256) void kSeries(const float* x, float* ws){
  __shared__ float sm[192];
  __shared__ float red[256];
  int n = blockIdx.x, tid = threadIdx.x;
  if (tid < 192){
    float acc = 0.f;
    size_t base = (size_t)n*192 + tid;
    for (int b = 0; b < 16; ++b) acc += x[base + (size_t)b*196608];
    sm[tid] = acc;
  }
  __syncthreads();
  float sval = 0.f;
  if (tid < 96) sval = (sm[2*tid] + sm[2*tid+1]) * (1.f/32.f);
  red[tid] = (tid < 96) ? sval : 0.f; __syncthreads();
  for (int s = 128; s > 0; s >>= 1){ if (tid < s) red[tid] += red[tid+s]; __syncthreads(); }
  float mu = red[0] * (1.f/96.f); __syncthreads();
  red[tid] = (tid < 96) ? sval*sval : 0.f; __syncthreads();
  for (int s = 128; s > 0; s >>= 1){ if (tid < s) red[tid] += red[tid+s]; __syncthreads(); }
  float nrm = sqrtf(red[0]); __syncthreads();
  float dev = sval - mu;
  red[tid] = (tid < 96) ? dev*dev : 0.f; __syncthreads();
  for (int s = 128; s > 0; s >>= 1){ if (tid < s) red[tid] += red[tid+s]; __syncthreads(); }
  float sd = sqrtf(red[0] * (1.f/96.f));
  if (tid < 96){
    ws[O_S  + (size_t)n*96 + tid] = sval;
    ws[O_SN + (size_t)n*96 + tid] = dev / (sd + EPS);
  }
  if (tid == 0){ ws[O_MU+n] = mu; ws[O_SD+n] = sd; ws[O_NRM+n] = nrm; }
}

// ---------------- c0 / cl correlation matrices ----------------
__global__ __launch_bounds__(256) void kCorr(float* ws){
  __shared__ float A[16][97], B[16][97];
  int bi = blockIdx.x, bj = blockIdx.y, tid = threadIdx.x;
  for (int l = tid; l < 16*96; l += 256){
    int r = l / 96, t = l % 96;
    A[r][t] = ws[O_SN + (size_t)(bi*16+r)*96 + t];
    B[r][t] = ws[O_SN + (size_t)(bj*16+r)*96 + t];
  }
  __syncthreads();
  int ti = tid >> 4, tj = tid & 15;
  int i = bi*16 + ti, j = bj*16 + tj;
  float c0 = 0.f, cl = 0.f;
  for (int t = 0; t < 96; ++t) c0 += A[ti][t]*B[tj][t];
  for (int t = 0; t < 95; ++t) cl += A[ti][t]*B[tj][t+1];
  ws[O_C0 + (size_t)i*N_ + j] = c0 * (1.f/96.f);
  ws[O_CL + (size_t)i*N_ + j] = cl * (1.f/95.f);
}

// ---------------- R ----------------
__global__ __launch_bounds__(256) void kR(float* ws){
  __shared__ float tl[32][33];
  int bi = blockIdx.x, bj = blockIdx.y, tid = threadIdx.x;
  for (int l = tid; l < 1024; l += 256){
    int r = l >> 5, c = l & 31;
    tl[r][c] = ws[O_CL + (size_t)(bj*32+r)*N_ + bi*32 + c];
  }
  __syncthreads();
  for (int l = tid; l < 1024; l += 256){
    int il = l >> 5, jl = l & 31;
    int i = bi*32 + il, j = bj*32 + jl;
    float c0 = ws[O_C0 + (size_t)i*N_ + j];
    float cl = ws[O_CL + (size_t)i*N_ + j];
    float clt = tl[jl][il];
    ws[O_R + (size_t)i*N_ + j] = 0.5f*(fabsf(c0) + fabsf(0.5f*(cl + clt)));
  }
}

// ---------------- per-row top-20 ----------------
__global__ __launch_bounds__(256) void kTopK(float* ws){
  __shared__ float v[1024];
  __shared__ float rv[256];
  __shared__ int ri[256];
  int r = blockIdx.x, tid = threadIdx.x;
  for (int l = tid; l < 1024; l += 256) v[l] = ws[O_R + (size_t)r*N_ + l];
  __syncthreads();
  if (tid == 0) v[r] = -3.4e38f;
  __syncthreads();
  int* idx = (int*)(ws + O_IDX);
  for (int t = 0; t < 20; ++t){
    float best = -3.4e38f; int bi = 1 << 30;
    for (int l = tid; l < 1024; l += 256){
      float vv = v[l];
      if (vv > best || (vv == best && l < bi)){ best = vv; bi = l; }
    }
    rv[tid] = best; ri[tid] = bi; __syncthreads();
    for (int s = 128; s > 0; s >>= 1){
      if (tid < s){
        if (rv[tid+s] > rv[tid] || (rv[tid+s] == rv[tid] && ri[tid+s] < ri[tid])){
          rv[tid] = rv[tid+s]; ri[tid] = ri[tid+s];
        }
      }
      __syncthreads();
    }
    if (tid == 0){ idx[r*20 + t] = ri[0]; v[ri[0]] = -3.4e38f; }
    __syncthreads();
  }
}

// ---------------- persistent Lanczos: 96 steps, CGS2, 3 barriers/step --------
// R5/R7-proven version (verbatim): LDS-staged R rows + own V column-slice
// (fence-immune); dot partials [KRY][GRID] (per-thread-contiguous reads);
// slots norm path. This configuration measured 1829 us.
__global__ __launch_bounds__(256) void kLanczos(float* ws){
  unsigned* bar = (unsigned*)(ws + O_BARL);
  __shared__ __align__(16) float Rl[16][1024];   // 64 KB: this block's R rows
  __shared__ float Vsl[KRY][16];                 // 6 KB: own V column-slice
  __shared__ float vsh[1024];
  __shared__ float red[272];
  __shared__ float yls[16];      // own slice of y
  __shared__ float csh[KRY];     // reduced CGS coefficients
  const int b = blockIdx.x, tid = threadIdx.x;
  const int i0 = b*16;
  float* slots = ws + O_NSLOT;
  float* dot0  = ws + O_DOT0;
  float* dot1  = ws + O_DOT1;
  float* y     = ws + O_YA;

  // prologue: stage R rows into LDS (once), v0 into y slice + partial sumsq
  {
    const f4* src = (const f4*)(ws + O_R + (size_t)i0*N_);   // 16 contiguous rows
    f4* dst = (f4*)&Rl[0][0];
    for (int l = tid; l < 4096; l += 256) dst[l] = src[l];
  }
  {
    float ss = 0.f;
    if (tid < 16){
      float v = hashf((unsigned)(i0 + tid + 12345));
      y[i0 + tid] = v;
      ss = v*v;
    }
    red[tid] = ss; __syncthreads();
    for (int s = 128; s > 0; s >>= 1){ if (tid < s) red[tid] += red[tid+s]; __syncthreads(); }
    if (tid == 0) slots[b] = red[0];
  }
  gbar(bar);

  for (int k = 0; k < KRY; ++k){
    // ---- phase A: normalize y -> v_k, matvec (LDS R), pass-0 partials ----
    {
      float t = (tid < GRID) ? slots[tid] : 0.f;
      red[tid] = t; __syncthreads();
      for (int s = 128; s > 0; s >>= 1){ if (tid < s) red[tid] += red[tid+s]; __syncthreads(); }
      float inv = rsqrtf(fmaxf(red[0], 1e-30f));
      __syncthreads();
      for (int l = tid; l < 1024; l += 256) vsh[l] = y[l]*inv;
      __syncthreads();
      if (tid < 16){
        float vk = vsh[i0 + tid];
        ws[O_V + (size_t)k*N_ + i0 + tid] = vk;   // for kRitz
        Vsl[k][tid] = vk;
      }
      int wave = tid >> 6, lane = tid & 63;
      for (int rr = 0; rr < 4; ++rr){
        const float* row = &Rl[wave*4 + rr][0];
        float acc = 0.f;
        for (int t2 = lane; t2 < 1024; t2 += 64) acc += row[t2]*vsh[t2];
        for (int off = 32; off > 0; off >>= 1) acc += __shfl_down(acc, off, 64);
        if (lane == 0) yls[wave*4 + rr] = acc;
      }
      __syncthreads();
      if (tid <= k){
        float acc = 0.f;
        #pragma unroll
        for (int q = 0; q < 16; ++q) acc += Vsl[tid][q]*yls[q];
        dot0[tid*GRID + b] = acc;
      }
    }
    gbar(bar);
    // ---- phase B: reduce c (+alpha/beta), local axpy0, pass-1 partials -----
    {
      if (tid <= k){
        const float* pr = dot0 + (size_t)tid*GRID;
        float acc = 0.f;
        #pragma unroll
        for (int q = 0; q < GRID; ++q) acc += pr[q];
        csh[tid] = acc;
        if (b == 0){
          if (tid == k)   ws[O_ALP + k] = acc;
          if (tid == k-1) ws[O_BET + k] = acc;
        }
      }
      __syncthreads();
      if (k == KRY-1) break;   // last step: only alpha/beta needed
      int il = tid & 15, chunk = tid >> 4;
      float part = 0.f;
      for (int j = chunk; j <= k; j += 16) part += csh[j]*Vsl[j][il];
      red[il*17 + chunk] = part;
      __syncthreads();
      if (tid < 16){
        float corr = 0.f;
        #pragma unroll
        for (int q = 0; q < 16; ++q) corr += red[tid*17 + q];
        yls[tid] -= corr;
      }
      __syncthreads();
      if (tid <= k){
        float acc = 0.f;
        #pragma unroll
        for (int q = 0; q < 16; ++q) acc += Vsl[tid][q]*yls[q];
        dot1[tid*GRID + b] = acc;
      }
    }
    gbar(bar);
    // ---- phase C: reduce c', local axpy1, publish y slice + norm partial ---
    {
      if (tid <= k){
        const float* pr = dot1 + (size_t)tid*GRID;
        float acc = 0.f;
        #pragma unroll
        for (int q = 0; q < GRID; ++q) acc += pr[q];
        csh[tid] = acc;
      }
      __syncthreads();
      int il = tid & 15, chunk = tid >> 4;
      float part = 0.f;
      for (int j = chunk; j <= k; j += 16) part += csh[j]*Vsl[j][il];
      red[il*17 + chunk] = part;
      __syncthreads();
      if (tid < 16){
        float corr = 0.f;
        #pragma unroll
        for (int q = 0; q < 16; ++q) corr += red[tid*17 + q];
        float nv = yls[tid] - corr;
        yls[tid] = nv;
        y[i0 + tid] = nv;
        red[tid*17 + 16] = nv*nv;
      }
      __syncthreads();
      if (tid == 0){
        float ss = 0.f;
        #pragma unroll
        for (int q = 0; q < 16; ++q) ss += red[q*17 + 16];
        slots[b] = ss;
      }
    }
    gbar(bar);
  }
}

// ---------------- T eigensolve (KRY=96): bisection + inverse iteration ----------------
__global__ __launch_bounds__(256) void kEigen(float* ws, const float* srcsig, const float* srcB){
  __shared__ float a[KRY], bt[KRY], b2[KRY], ev[KRY];
  __shared__ float Dw[16][KRY], U1w[16][KRY], U2w[16][KRY], Xw[16][KRY];
  __shared__ int slotidx[16];
  __shared__ float slam[16];
  __shared__ float glo_s, ghi_s;
  int tid = threadIdx.x;
  if (tid < KRY){
    a[tid] = ws[O_ALP + tid];
    float b = (tid >= 1) ? ws[O_BET + tid] : 0.f;
    bt[tid] = b; b2[tid] = b*b;
  }
  __syncthreads();
  if (tid == 0){
    float lo = 3.4e38f, hi = -3.4e38f;
    for (int i = 0; i < KRY; ++i){
      float r = fabsf(bt[i]) + ((i < KRY-1) ? fabsf(bt[i+1]) : 0.f);
      lo = fminf(lo, a[i] - r); hi = fmaxf(hi, a[i] + r);
    }
    glo_s = lo - 1.f; ghi_s = hi + 1.f;
  }
  __syncthreads();
  if (tid < KRY){
    float lo = glo_s, hi = ghi_s;
    for (int it = 0; it < 60; ++it){
      float mid = 0.5f*(lo + hi);
      int cnt = 0; float d = 1.f;
      for (int kk = 0; kk < KRY; ++kk){
        d = (a[kk] - mid) - ((kk > 0) ? b2[kk]/d : 0.f);
        if (d < 0.f) cnt++;
        if (fabsf(d) < 1e-20f) d = -1e-20f;
      }
      if (cnt <= tid) lo = mid; else hi = mid;
    }
    ev[tid] = 0.5f*(lo + hi);
    ws[O_EV + tid] = ev[tid];
  }
  __syncthreads();
  if (tid == 0){
    int hiI = KRY-1, loI = 0;
    float topv[16]; int magidx[16];
    for (int t = 0; t < 16; ++t){
      if (fabsf(ev[hiI]) >= fabsf(ev[loI])) magidx[t] = hiI--;
      else magidx[t] = loI++;
      topv[t] = fabsf(ev[magidx[t]]);
    }
    for (int s = 0; s < 8; ++s){ slotidx[s] = magidx[s]; slam[s] = ev[magidx[s]]; }
    for (int s = 0; s < 8; ++s){ slotidx[8+s] = KRY-8 + s; slam[8+s] = ev[KRY-8+s]; }
    float t0 = topv[0] + EPS;
    float sig[4];
    for (int m = 0; m < 4; ++m){
      float acc = 0.f;
      for (int t = 0; t < 16; ++t){
        float x = topv[t]/t0, p = x;
        for (int q = 0; q < m; ++q) p *= x;
        acc += p;
      }
      sig[m] = acc * (1.f/16.f);
    }
    float dist[3];
    for (int m = 0; m < 3; ++m){
      float acc = 0.f;
      for (int kq = 0; kq < 4; ++kq){ float dd = srcsig[m*4+kq] - sig[kq]; acc += dd*dd; }
      dist[m] = acc;
    }
    float mx = fmaxf(fmaxf(-dist[0], -dist[1]), -dist[2]);
    float e0 = expf(-dist[0]-mx), e1 = expf(-dist[1]-mx), e2 = expf(-dist[2]-mx);
    float sinv = 1.f/(e0+e1+e2);
    float rho0 = e0*sinv, rho1 = e1*sinv, rho2 = e2*sinv;
    for (int rr = 0; rr < 8; ++rr)
      for (int ss = 0; ss < 8; ++ss)
        ws[O_BEFF + rr*8 + ss] = rho0*srcB[rr*8+ss] + rho1*srcB[64+rr*8+ss] + rho2*srcB[128+rr*8+ss];
    for (int s = 0; s < 16; ++s) ws[O_LS + s] = slam[s];
  }
  __syncthreads();
  if (tid < 16){
    int s = tid, ei = slotidx[s];
    float lam = ev[ei];
    for (int pass = 0; pass < 2; ++pass){
      for (int i = 0; i < KRY; ++i){
        Dw[s][i] = a[i] - lam;
        U1w[s][i] = (i < KRY-1) ? bt[i+1] : 0.f;
        U2w[s][i] = 0.f;
        if (pass == 0) Xw[s][i] = hashf((unsigned)(ei*1024 + i + 777));
      }
      for (int i = 0; i < KRY-1; ++i){
        float p1 = Dw[s][i], q1 = U1w[s][i], r1 = U2w[s][i], x1 = Xw[s][i];
        float p2 = bt[i+1], q2 = Dw[s][i+1], rr2 = U1w[s][i+1], x2 = Xw[s][i+1];
        if (fabsf(p2) > fabsf(p1)){
          float t;
          t=p1;p1=p2;p2=t; t=q1;q1=q2;q2=t; t=r1;r1=rr2;rr2=t; t=x1;x1=x2;x2=t;
        }
        if (fabsf(p1) < 1e-20f) p1 = (p1 < 0.f) ? -1e-20f : 1e-20f;
        float m = p2/p1;
        Dw[s][i]=p1; U1w[s][i]=q1; U2w[s][i]=r1; Xw[s][i]=x1;
        Dw[s][i+1] = q2 - m*q1; U1w[s][i+1] = rr2 - m*r1; Xw[s][i+1] = x2 - m*x1;
      }
      {
        float dd = Dw[s][KRY-1]; if (fabsf(dd) < 1e-20f) dd = 1e-20f;
        Xw[s][KRY-1] = Xw[s][KRY-1]/dd;
      }
      {
        float dd = Dw[s][KRY-2]; if (fabsf(dd) < 1e-20f) dd = 1e-20f;
        Xw[s][KRY-2] = (Xw[s][KRY-2] - U1w[s][KRY-2]*Xw[s][KRY-1])/dd;
      }
      for (int i = KRY-3; i >= 0; --i){
        float dd = Dw[s][i]; if (fabsf(dd) < 1e-20f) dd = 1e-20f;
        Xw[s][i] = (Xw[s][i] - U1w[s][i]*Xw[s][i+1] - U2w[s][i]*Xw[s][i+2])/dd;
      }
      float nn = 0.f;
      for (int i = 0; i < KRY; ++i) nn += Xw[s][i]*Xw[s][i];
      float inv = rsqrtf(fmaxf(nn, 1e-37f));
      for (int i = 0; i < KRY; ++i) Xw[s][i] *= inv;
    }
  }
  __syncthreads();
  if (tid == 0){
    for (int s = 1; s < 16; ++s)
      for (int t = 0; t < s; ++t){
        if (slotidx[t] == slotidx[s]) continue;
        if (fabsf(slam[t] - slam[s]) > 1e-2f) continue;
        float dp = 0.f;
        for (int i = 0; i < KRY; ++i) dp += Xw[s][i]*Xw[t][i];
        for (int i = 0; i < KRY; ++i) Xw[s][i] -= dp*Xw[t][i];
        float nn = 0.f;
        for (int i = 0; i < KRY; ++i) nn += Xw[s][i]*Xw[s][i];
        float inv = rsqrtf(fmaxf(nn, 1e-37f));
        for (int i = 0; i < KRY; ++i) Xw[s][i] *= inv;
      }
  }
  __syncthreads();
  for (int l = tid; l < 16*KRY; l += 256) ws[O_YS + l] = Xw[l/KRY][l%KRY];
}

// ---------------- Ritz vectors: Umag (slots 0..7), W0 row-major (slots 8..15) ----------------
__global__ __launch_bounds__(256) void kRitz(float* ws){
  __shared__ float ysh[16][KRY];
  __shared__ float lam[16];
  int tid = threadIdx.x;
  for (int l = tid; l < 16*KRY; l += 256) ysh[l/KRY][l%KRY] = ws[O_YS + l];
  if (tid < 16) lam[tid] = ws[O_LS + tid];
  __syncthreads();
  int i = blockIdx.x*256 + tid;
  float acc[16];
  #pragma unroll
  for (int s = 0; s < 16; ++s) acc[s] = 0.f;
  for (int k = 0; k < KRY; ++k){
    float v = ws[O_V + (size_t)k*N_ + i];
    #pragma unroll
    for (int s = 0; s < 16; ++s) acc[s] += v*ysh[s][k];
  }
  #pragma unroll
  for (int s = 0; s < 8; ++s) ws[O_UM + (size_t)i*8 + s] = acc[s];
  #pragma unroll
  for (int c = 0; c < 8; ++c) ws[O_WA + (size_t)i*8 + c] = sqrtf(fabsf(lam[8+c]))*fabsf(acc[8+c]);
}

// ---------------- |L| + global max ----------------
__global__ __launch_bounds__(256) void kL(float* ws){
  __shared__ float Ua[32][8], Ub[32][8], lam[8];
  __shared__ float red[256];
  int bi = blockIdx.x, bj = blockIdx.y, tid = threadIdx.x;
  if (tid < 8) lam[tid] = ws[O_LS + tid];
  int r = tid >> 3, c = tid & 7;
  Ua[r][c] = ws[O_UM + (size_t)(bi*32+r)*8 + c];
  Ub[r][c] = ws[O_UM + (size_t)(bj*32+r)*8 + c];
  __syncthreads();
  float bmax = 0.f;
  for (int l = tid; l < 1024; l += 256){
    int il = l >> 5, jl = l & 31;
    int i = bi*32 + il, j = bj*32 + jl;
    float acc = 0.f;
    #pragma unroll
    for (int q = 0; q < 8; ++q) acc += lam[q]*Ua[il][q]*Ub[jl][q];
    float v = fabsf(acc);
    if (i == j) v = 0.f;
    ws[O_AL + (size_t)i*N_ + j] = v;
    bmax = fmaxf(bmax, v);
  }
  red[tid] = bmax; __syncthreads();
  for (int s = 128; s > 0; s >>= 1){ if (tid < s) red[tid] = fmaxf(red[tid], red[tid+s]); __syncthreads(); }
  if (tid == 0) atomicMax((int*)(ws + O_SCAL + 0), __float_as_int(red[0]));
}

// ---------------- per-row scaled max + softmax denom ----------------
__global__ __launch_bounds__(256) void kRowStats(float* ws, int which){
  __shared__ float red[256];
  size_t src = which ? O_AP : O_AL;
  float mxall = __int_as_float(((int*)(ws + O_SCAL))[which]);
  float d = 1.f/(mxall + EPS);
  int r = blockIdx.x, tid = threadIdx.x;
  const float* row = ws + src + (size_t)r*N_;
  float m = 0.f;
  for (int l = tid; l < 1024; l += 256) m = fmaxf(m, row[l]);
  red[tid] = m; __syncthreads();
  for (int s = 128; s > 0; s >>= 1){ if (tid < s) red[tid] = fmaxf(red[tid], red[tid+s]); __syncthreads(); }
  float rmax = red[0]*d; __syncthreads();
  float acc = 0.f;
  for (int l = tid; l < 1024; l += 256){ float v = row[l]; if (v != 0.f) acc += expf(v*d - rmax); }
  red[tid] = acc; __syncthreads();
  for (int s = 128; s > 0; s >>= 1){ if (tid < s) red[tid] += red[tid+s]; __syncthreads(); }
  if (tid == 0){
    ws[(which ? O_RMP : O_RML) + r] = rmax;
    ws[(which ? O_RDP : O_RDL) + r] = red[0];
  }
}

// ---------------- persistent NMF: 80 clamped-GD iterations ----------------
// R rows in LDS (loaded once, fence-immune); W padded to stride 9 (9 coprime
// to 32 banks -> the stride-8 16-way conflicts in G/RW loops vanish).
__global__ __launch_bounds__(256) void kNmf(float* ws){
  unsigned* bar = (unsigned*)(ws + O_BARN);
  __shared__ __align__(16) float Rl[16][1028];   // 64.3 KB, stride 1028 spreads banks
  __shared__ float Wl[1024][9];   // 36 KB, padded stride
  __shared__ float G[64];
  __shared__ float red2[256];
  int b = blockIdx.x, tid = threadIdx.x;
  int r0 = b*16;
  {
    for (int l = tid; l < 4096; l += 256){
      int r = l >> 8, t4 = l & 255;
      ((f4*)&Rl[r][0])[t4] = ((const f4*)(ws + O_R + (size_t)(r0+r)*N_))[t4];
    }
  }
  for (int it = 0; it < 80; ++it){
    const float* Win = ws + ((it & 1) ? O_WB : O_WA);
    float* Wout      = ws + ((it & 1) ? O_WA : O_WB);
    for (int l = tid; l < 8192; l += 256) Wl[l >> 3][l & 7] = Win[l];
    __syncthreads();
    // G = W^T W  (redundant per block, deterministic)
    {
      int p = tid >> 2, q = tid & 3;
      int rr = p >> 3, cc = p & 7;
      float acc = 0.f;
      for (int t = q*256; t < q*256 + 256; ++t) acc += Wl[t][rr]*Wl[t][cc];
      red2[tid] = acc; __syncthreads();
      if (q == 0) G[p] = red2[tid] + red2[tid+1] + red2[tid+2] + red2[tid+3];
      __syncthreads();
    }
    // RW + update for own 16 rows (R from LDS)
    {
      int half = tid & 1;
      int pr = tid >> 1;            // 0..127 = (lr, j)
      int lr = pr >> 3, j = pr & 7;
      int grow = r0 + lr;
      const float* rrow = &Rl[lr][0];
      float acc = 0.f;
      for (int t = half*512; t < half*512 + 512; ++t) acc += rrow[t]*Wl[t][j];
      red2[tid] = acc; __syncthreads();
      if (half == 0){
        float rw = red2[tid] + red2[tid+1];
        float wg = 0.f;
        #pragma unroll
        for (int c = 0; c < 8; ++c) wg += Wl[grow][c]*G[c*8 + j];
        float val = Wl[grow][j] - 0.2f*(wg - rw);
        Wout[(size_t)grow*8 + j] = fmaxf(val, 0.f);
      }
      __syncthreads();
    }
    if (it != 79) gbar(bar);   // kernel boundary covers the last iteration
  }
}

// ---------------- |W Beff W^T| + global max (Wb folded in) ----------------
__global__ __launch_bounds__(256) void kP(float* ws){
  __shared__ float B[64];
  __shared__ float Wa[8][32], Wb2[8][32];
  __shared__ float red[256];
  int bi = blockIdx.x, bj = blockIdx.y, tid = threadIdx.x;
  if (tid < 64) B[tid] = ws[O_BEFF + tid];
  __syncthreads();
  {
    int c = tid >> 5, il = tid & 31;
    Wb2[c][il] = ws[O_WA + (size_t)(bj*32+il)*8 + c];
  }
  __syncthreads();
  {
    int r = tid >> 5, il = tid & 31;
    float acc = 0.f;
    #pragma unroll
    for (int c = 0; c < 8; ++c) acc += ws[O_WA + (size_t)(bi*32+il)*8 + c]*B[c*8 + r];
    Wa[r][il] = acc;
  }
  __syncthreads();
  float bmax = 0.f;
  for (int l = tid; l < 1024; l += 256){
    int il = l >> 5, jl = l & 31;
    int i = bi*32+il, j = bj*32+jl;
    float acc = 0.f;
    #pragma unroll
    for (int q = 0; q < 8; ++q) acc += Wa[q][il]*Wb2[q][jl];
    float v = fabsf(acc);
    if (i == j) v = 0.f;
    ws[O_AP + (size_t)i*N_ + j] = v;
    bmax = fmaxf(bmax, v);
  }
  red[tid] = bmax; __syncthreads();
  for (int s = 128; s > 0; s >>= 1){ if (tid < s) red[tid] = fmaxf(red[tid], red[tid+s]); __syncthreads(); }
  if (tid == 0) atomicMax((int*)(ws + O_SCAL + 1), __float_as_int(red[0]));
}

// ---------------- edge scores ----------------
__global__ __launch_bounds__(256) void kEdges(float* ws, const float* w1, const float* b1,
                                              const float* w2, const float* b2){
  __shared__ float W1[256], B1[32], W2[32], B2;
  int tid = threadIdx.x;
  if (tid < 256) W1[tid] = w1[tid];
  if (tid < 32){ B1[tid] = b1[tid]; W2[tid] = w2[tid]; }
  if (tid == 0) B2 = b2[0];
  __syncthreads();
  int e = blockIdx.x*256 + tid;
  if (e >= EDG) return;
  int r = e/20;
  int c = ((const int*)(ws + O_IDX))[e];
  float dL = 1.f/(__int_as_float(((int*)(ws+O_SCAL))[0]) + EPS);
  float aL = ws[O_AL + (size_t)r*N_ + c];
  float slr = 0.f;
  if (aL != 0.f){ float den = ws[O_RDL + r]; if (den > 0.f) slr = expf(aL*dL - ws[O_RML + r])/den; }
  float dP = 1.f/(__int_as_float(((int*)(ws+O_SCAL))[1]) + EPS);
  float aP = ws[O_AP + (size_t)r*N_ + c];
  float sro = 0.f;
  if (aP != 0.f){ float den = ws[O_RDP + r]; if (den > 0.f) sro = expf(aP*dP - ws[O_RMP + r])/den; }
  float dots = 0.f;
  const float* srow = ws + O_S + (size_t)r*T_;
  const float* scol = ws + O_S + (size_t)c*T_;
  for (int t = 0; t < 96; ++t) dots += srow[t]*scol[t];
  float cosm = dots/(ws[O_NRM+r]*ws[O_NRM+c] + EPS);
  float f[8];
  f[0] = ws[O_C0 + (size_t)r*N_ + c];
  f[1] = ws[O_CL + (size_t)r*N_ + c];
  f[2] = ws[O_CL + (size_t)c*N_ + r];
  f[3] = cosm;
  f[4] = ws[O_MU + r]; f[5] = ws[O_MU + c];
  f[6] = ws[O_SD + r]; f[7] = ws[O_SD + c];
  float sres = B2;
  for (int jj = 0; jj < 32; ++jj){
    float h = B1[jj];
    #pragma unroll
    for (int q = 0; q < 8; ++q) h += f[q]*W1[q*32 + jj];
    h = fmaxf(h, 0.f);
    sres += h*W2[jj];
  }
  ws[O_SLR + e] = slr; ws[O_SRO + e] = sro; ws[O_SRE + e] = sres;
}

// ---------------- mean / inv-std of score arrays ----------------
__global__ __launch_bounds__(1024) void kStats(float* ws){
  __shared__ float red[1024];
  int tid = threadIdx.x;
  for (int arr = 0; arr < 3; ++arr){
    const float* x = (arr == 0) ? ws + O_SLR : ((arr == 1) ? ws + O_SRO : ws + O_SRE);
    float acc = 0.f;
    for (int l = tid; l < EDG; l += 1024) acc += x[l];
    red[tid] = acc; __syncthreads();
    for (int s = 512; s > 0; s >>= 1){ if (tid < s) red[tid] += red[tid+s]; __syncthreads(); }
    float mean = red[0]/(float)EDG; __syncthreads();
    float acc2 = 0.f;
    for (int l = tid; l < EDG; l += 1024){ float d = x[l]-mean; acc2 += d*d; }
    red[tid] = acc2; __syncthreads();
    for (int s = 512; s > 0; s >>= 1){ if (tid < s) red[tid] += red[tid+s]; __syncthreads(); }
    if (tid == 0){
      float var = red[0]/(float)EDG;
      ws[O_SCAL + 2 + arr*2] = mean;
      ws[O_SCAL + 3 + arr*2] = 1.f/(sqrtf(var) + EPS);
    }
    __syncthreads();
  }
}

// ---------------- final output ----------------
__global__ __launch_bounds__(256) void kOut(float* ws, float* out){
  __shared__ __align__(16) float row[1024];
  __shared__ float sv[20];
  __shared__ int cols[20];
  int r = blockIdx.x, tid = threadIdx.x;
  for (int l = tid; l < 1024; l += 256) row[l] = 0.f;
  if (tid < 20){
    int e = r*20 + tid;
    float m1 = ws[O_SCAL+2], k1 = ws[O_SCAL+3];
    float m2 = ws[O_SCAL+4], k2 = ws[O_SCAL+5];
    float m3 = ws[O_SCAL+6], k3 = ws[O_SCAL+7];
    float v = 0.3f*(ws[O_SLR+e]-m1)*k1 + 0.4f*(ws[O_SRO+e]-m2)*k2 + 0.1f*(ws[O_SRE+e]-m3)*k3;
    sv[tid] = 1.f/(1.f + expf(-v));
    cols[tid] = ((const int*)(ws + O_IDX))[e];
  }
  __syncthreads();
  if (tid == 0){
    float mx = sv[0];
    for (int q = 1; q < 20; ++q) mx = fmaxf(mx, sv[q]);
    float den = 0.f; float ex[20];
    for (int q = 0; q < 20; ++q){ ex[q] = expf(sv[q]-mx); den += ex[q]; }
    float inv = 1.f/den;
    for (int q = 0; q < 20; ++q) row[cols[q]] = ex[q]*inv;
  }
  __syncthreads();
  const float4* r4 = (const float4*)row;
  for (int b = 0; b < 16; ++b){
    float4* dst = (float4*)(out + (size_t)b*1048576 + (size_t)r*1024);
    dst[tid] = r4[tid];
  }
}

extern "C" void kernel_launch(void* const* d_in, const int* in_sizes, int n_in,
                              void* d_out, int out_size, void* d_ws, size_t ws_size,
                              hipStream_t stream) {
  (void)in_sizes; (void)n_in; (void)out_size; (void)ws_size;
  const float* x   = (const float*)d_in[0];
  const float* sig = (const float*)d_in[2];
  const float* rB  = (const float*)d_in[3];
  const float* w1  = (const float*)d_in[4];
  const float* b1  = (const float*)d_in[5];
  const float* w2  = (const float*)d_in[6];
  const float* b2  = (const float*)d_in[7];
  float* w = (float*)d_ws;
  float* out = (float*)d_out;

  kInit<<<1, 1024, 0, stream>>>(w);
  kSeries<<<1024, 256, 0, stream>>>(x, w);
  kCorr<<<dim3(64,64), 256, 0, stream>>>(w);
  kR<<<dim3(32,32), 256, 0, stream>>>(w);
  kTopK<<<1024, 256, 0, stream>>>(w);

  kLanczos<<<GRID, 256, 0, stream>>>(w);     // 96-step CGS2 Lanczos (proven-best config)
  kEigen<<<1, 256, 0, stream>>>(w, sig, rB);
  kRitz<<<4, 256, 0, stream>>>(w);

  kL<<<dim3(32,32), 256, 0, stream>>>(w);
  kRowStats<<<1024, 256, 0, stream>>>(w, 0);

  kNmf<<<GRID, 256, 0, stream>>>(w);         // 80 iterations, padded W in LDS
  kP<<<dim3(32,32), 256, 0, stream>>>(w);
  kRowStats<<<1024, 256, 0, stream>>>(w, 1);

  kEdges<<<80, 256, 0, stream>>>(w, w1, b1, w2, b2);
  kStats<<<1, 1024, 0, stream>>>(w);
  kOut<<<1024, 256, 0, stream>>>(w, out);
}